// Round 9
// baseline (947.522 us; speedup 1.0000x reference)
//
#include <hip/hip_runtime.h>
#include <hip/hip_bf16.h>
#include <math.h>

#define NTH 256

typedef __bf16 bf16x8 __attribute__((ext_vector_type(8)));
typedef float  f32x4  __attribute__((ext_vector_type(4)));
typedef unsigned short ushort;
typedef ushort u16x8 __attribute__((ext_vector_type(8)));

// native RNE float->bf16 (v_cvt_pk_bf16_f32)
__device__ __forceinline__ ushort f2bf(float x){
    union { __bf16 b; ushort u; } v;
    v.b = (__bf16)x;
    return v.u;
}
__device__ __forceinline__ float bf2f(ushort h){
    union { unsigned int u; float f; } v; v.u = ((unsigned int)h) << 16;
    return v.f;
}

// ============================ prep kernels ============================
__global__ void prep_combined_bf(const float* __restrict__ Wq, const float* __restrict__ Wk,
                                 const float* __restrict__ Wv, const float* __restrict__ in_w,
                                 ushort* __restrict__ dh)
{
    int o = blockIdx.x*NTH + threadIdx.x;
    if (o >= 76800) return;
    int c = o/160, j = o - c*160;
    const float* Wsel = (c<160) ? Wq : (c<320) ? Wk : Wv;
    const float* wrow = Wsel + j*160;
    const float* irow = in_w + c*160;
    float s = 0.f;
    for (int k=0;k<160;k++) s = fmaf(wrow[k], irow[k], s);
    dh[o] = f2bf(s);
}

__global__ void prep_H_split(const float* __restrict__ f_in_w, const float* __restrict__ out_w,
                             ushort* __restrict__ dh, float* __restrict__ tmp)
{
    int o = blockIdx.x*NTH + threadIdx.x;
    if (o >= 76800) return;
    int n = o/160, k = o - n*160;
    float s = 0.f;
    for (int c=0;c<160;c++) s = fmaf(f_in_w[n*160+c], out_w[c*160+k], s);
    if (n < 320) dh[o] = f2bf(s);
    else         tmp[(n-320)*160 + k] = s;
}

__global__ void prep_H_fold(const float* __restrict__ fo, const float* __restrict__ Hv,
                            ushort* __restrict__ dh)
{
    int o = blockIdx.x*NTH + threadIdx.x;
    if (o >= 25600) return;
    int n = o/160, k = o - n*160;
    float s = 0.f;
    for (int j=0;j<160;j++) s = fmaf(fo[n*160+j], Hv[j*160+k], s);
    dh[(320+n)*160 + k] = f2bf(s);
}

__global__ void prep_cvec(const float* __restrict__ f_in_w, const float* __restrict__ out_b,
                          const float* __restrict__ f_in_b, float* __restrict__ cvt)
{
    int n = blockIdx.x*NTH + threadIdx.x;
    if (n >= 480) return;
    float s = f_in_b[n];
    for (int c=0;c<160;c++) s = fmaf(f_in_w[n*160+c], out_b[c], s);
    cvt[n] = s;
}

__global__ void prep_cvec_fold(const float* __restrict__ fo, const float* __restrict__ cvt,
                               float* __restrict__ cv)
{
    int n = blockIdx.x*NTH + threadIdx.x;
    if (n >= 480) return;
    if (n < 320){ cv[n] = cvt[n]; return; }
    int m = n - 320;
    float s = 0.f;
    for (int j=0;j<160;j++) s = fmaf(fo[m*160+j], cvt[320+j], s);
    cv[n] = s;
}

__global__ void prep_conv_bf1(const float* __restrict__ src, ushort* __restrict__ dh, int n)
{
    int o = blockIdx.x*NTH + threadIdx.x;
    if (o >= n) return;
    dh[o] = f2bf(src[o]);
}

__global__ void prep_conv_bf2(const float* __restrict__ src,
                              ushort* __restrict__ dh, ushort* __restrict__ dl, int n)
{
    int o = blockIdx.x*NTH + threadIdx.x;
    if (o >= n) return;
    float s = src[o];
    ushort h = f2bf(s);
    dh[o] = h; dl[o] = f2bf(s - bf2f(h));
}

// ============================ MFMA GEMM (fp32 A, split-x3) — final linear ============
__global__ __launch_bounds__(NTH)
void gemm_mfma_lin(const float* __restrict__ A,
                   const ushort* __restrict__ Wh, const ushort* __restrict__ Wl,
                   const float* __restrict__ bias, float* __restrict__ C, int N)
{
    __shared__ ushort sAh[128*40], sAl[128*40];
    __shared__ ushort sWh[160*40], sWl[160*40];

    const int tid = threadIdx.x;
    const int lane = tid & 63, wave = tid >> 6;
    const int wm = wave >> 1, wn = wave & 1;
    const int ln = lane & 15, g = lane >> 4;
    const long m0 = (long)blockIdx.x * 128;
    const int  n0 = blockIdx.y * 160;

    f32x4 acc[4][5];
#pragma unroll
    for (int mt=0;mt<4;mt++)
#pragma unroll
        for (int nt=0;nt<5;nt++)
#pragma unroll
            for (int r=0;r<4;r++) acc[mt][nt][r] = 0.f;

    for (int k0=0;k0<160;k0+=32){
#pragma unroll
        for (int i=0;i<4;i++){
            int f = tid + 256*i;
            int m = f >> 3, seg = f & 7;
            float4 v = *(const float4*)(A + (m0+m)*160 + k0 + seg*4);
            ushort4 hv, lv;
            hv.x = f2bf(v.x); lv.x = f2bf(v.x - bf2f(hv.x));
            hv.y = f2bf(v.y); lv.y = f2bf(v.y - bf2f(hv.y));
            hv.z = f2bf(v.z); lv.z = f2bf(v.z - bf2f(hv.z));
            hv.w = f2bf(v.w); lv.w = f2bf(v.w - bf2f(hv.w));
            *(ushort4*)(sAh + m*40 + seg*4) = hv;
            *(ushort4*)(sAl + m*40 + seg*4) = lv;
        }
#pragma unroll
        for (int i=0;i<5;i++){
            int e = tid + 256*i;
            int pl = (e >= 640);
            int idx = pl ? e-640 : e;
            int n = idx >> 2, seg = idx & 3;
            const ushort* src = (pl ? Wl : Wh) + (long)(n0+n)*160 + k0 + seg*8;
            ushort* dst = (pl ? sWl : sWh) + n*40 + seg*8;
            *(uint4*)dst = *(const uint4*)src;
        }
        __syncthreads();

        bf16x8 ah[4], al[4];
#pragma unroll
        for (int mt=0;mt<4;mt++){
            int off = (wm*64 + mt*16 + ln)*40 + g*8;
            ah[mt] = *(const bf16x8*)(sAh + off);
            al[mt] = *(const bf16x8*)(sAl + off);
        }
#pragma unroll
        for (int nt=0;nt<5;nt++){
            int offw = (wn*80 + nt*16 + ln)*40 + g*8;
            bf16x8 bh = *(const bf16x8*)(sWh + offw);
            bf16x8 bl = *(const bf16x8*)(sWl + offw);
#pragma unroll
            for (int mt=0;mt<4;mt++){
                acc[mt][nt] = __builtin_amdgcn_mfma_f32_16x16x32_bf16(ah[mt], bh, acc[mt][nt], 0,0,0);
                acc[mt][nt] = __builtin_amdgcn_mfma_f32_16x16x32_bf16(al[mt], bh, acc[mt][nt], 0,0,0);
                acc[mt][nt] = __builtin_amdgcn_mfma_f32_16x16x32_bf16(ah[mt], bl, acc[mt][nt], 0,0,0);
            }
        }
        __syncthreads();
    }

#pragma unroll
    for (int nt=0;nt<5;nt++){
        int col = n0 + wn*80 + nt*16 + ln;
        float bv = bias[col];
#pragma unroll
        for (int mt=0;mt<4;mt++){
#pragma unroll
            for (int r=0;r<4;r++){
                long row = m0 + wm*64 + mt*16 + g*4 + r;
                float x = acc[mt][nt][r] + bv;
                x = x > 0.f ? x : expm1f(x);
                C[row*N + col] = x;
            }
        }
    }
}

// ============================ bf16 GEMM (A bf16, W single-plane) — XP projection ======
__global__ __launch_bounds__(NTH)
void gemm_bf(const ushort* __restrict__ A0, const ushort* __restrict__ A1,
             const ushort* __restrict__ Wh0, const ushort* __restrict__ Wh1,
             const float* __restrict__ b0, const float* __restrict__ b1,
             ushort* __restrict__ C0, ushort* __restrict__ C1, int N)
{
    const int z = blockIdx.z;
    const ushort* A  = z ? A1 : A0;
    const ushort* Wh = z ? Wh1 : Wh0;
    const float* bias = z ? b1 : b0;
    ushort* C = z ? C1 : C0;

    __shared__ ushort sA[128*40];
    __shared__ ushort sW[160*40];

    const int tid = threadIdx.x;
    const int lane = tid & 63, wave = tid >> 6;
    const int wm = wave >> 1, wn = wave & 1;
    const int ln = lane & 15, g = lane >> 4;
    const long m0 = (long)blockIdx.x * 128;
    const int  n0 = blockIdx.y * 160;

    f32x4 acc[4][5];
#pragma unroll
    for (int mt=0;mt<4;mt++)
#pragma unroll
        for (int nt=0;nt<5;nt++)
#pragma unroll
            for (int r=0;r<4;r++) acc[mt][nt][r] = 0.f;

    for (int k0=0;k0<160;k0+=32){
#pragma unroll
        for (int i=0;i<2;i++){
            int e = tid + 256*i;
            int m = e >> 2, seg = e & 3;
            *(uint4*)(sA + m*40 + seg*8) =
                *(const uint4*)(A + (m0+m)*160 + k0 + seg*8);
        }
#pragma unroll
        for (int i=0;i<3;i++){
            int e = tid + 256*i;
            if (e < 640){
                int n = e >> 2, seg = e & 3;
                *(uint4*)(sW + n*40 + seg*8) =
                    *(const uint4*)(Wh + (long)(n0+n)*160 + k0 + seg*8);
            }
        }
        __syncthreads();

        bf16x8 af[4];
#pragma unroll
        for (int mt=0;mt<4;mt++)
            af[mt] = *(const bf16x8*)(sA + (wm*64 + mt*16 + ln)*40 + g*8);
#pragma unroll
        for (int nt=0;nt<5;nt++){
            bf16x8 bh = *(const bf16x8*)(sW + (wn*80 + nt*16 + ln)*40 + g*8);
#pragma unroll
            for (int mt=0;mt<4;mt++)
                acc[mt][nt] = __builtin_amdgcn_mfma_f32_16x16x32_bf16(af[mt], bh, acc[mt][nt], 0,0,0);
        }
        __syncthreads();
    }

#pragma unroll
    for (int nt=0;nt<5;nt++){
        int col = n0 + wn*80 + nt*16 + ln;
        float bv = bias[col];
#pragma unroll
        for (int mt=0;mt<4;mt++){
#pragma unroll
            for (int r=0;r<4;r++){
                long row = m0 + wm*64 + mt*16 + g*4 + r;
                C[row*N + col] = f2bf(acc[mt][nt][r] + bv);
            }
        }
    }
}

// ============================ MEGA: layer-attn x2 + FQ-gemm + final attn + pool =======
// ROUND-9: 1 node per block, 256 threads (4 waves), LDS peak 36352 B -> 4 blocks/CU.
// Rationale: round-8 showed VALUBusy drop (35->30) with FLAT time — latency-bound,
// not VALU-bound. Same 16 waves/CU but as 4 INDEPENDENT blocks: one block's
// gather/barrier windows hide behind 3 others' compute; barrier scope halves.
// Cost: H re-read doubles (10 GB L2 aggregate ~22 TB/s at projected dur — under the
// 34.5 TB/s ceiling). setprio dropped (unattributed in round 8).
//   Phase A (l=0,1): gather node's 16 XP rows into XPg; per-task fused attention
//     (5 head-tasks on 4 waves); O -> sO[layer] in LDS.
//   Phase B: wave (wl=w>>1, wn=w&1) pulls O fragments into VGPRs; barrier;
//     LDS repurposed.
//   Phase C: FQ^T gemm, cg = t*2+wn (30 col-groups); Q/K -> sFQ, V' -> sVt.
//   Phase D: final attention + max-pool (waves 0,1 = row-half).
#define XST 504
__global__ __launch_bounds__(NTH)
void mega_node(const ushort* __restrict__ XPi, const ushort* __restrict__ XPo,
               const int* __restrict__ in_idx, const int* __restrict__ out_idx,
               const ushort* __restrict__ Hi, const ushort* __restrict__ Ho,
               const float* __restrict__ c_i, const float* __restrict__ c_o,
               const float* __restrict__ fb, float* __restrict__ pooled)
{
    __shared__ ushort lds[18176];   // 36352 B

    const int tid  = threadIdx.x;
    const int lane = tid & 63, w = tid >> 6;       // wave 0..3
    const int ln = lane & 15, g = lane >> 4;
    // XCD-chunked swizzle: 32768 blocks = 8 batches x 4096
    const int node = ((int)blockIdx.x & 7) * 4096 + ((int)blockIdx.x >> 3);

    ushort* XPg = lds;              // 16 rows * 504 = 8064 us (16128 B)
    ushort* sO  = lds + 8064;       // 2 layers * 16 * 168 = 5376 us (10752 B)
    ushort* sPh = lds + 13440;      // 5 tasks * 384 = 1920 us (ends 15360)

    const int bb = node >> 12, nn = node & 4095;
    int idx0 = nn, idx1 = nn;
    if (lane >= 1 && lane < 16){
        idx0 = in_idx [(long)node*15 + lane-1];
        idx1 = out_idx[(long)node*15 + lane-1];
    }

    // ---------- stage layer0 -> LDS ----------
#pragma unroll
    for (int i=0;i<4;i++){
        int e = i*256 + tid;
        if (e < 960){
            int r = e/60, c = e - r*60;
            int rowg = __shfl(idx0, r);
            *(uint4*)(XPg + r*XST + c*8) =
                *(const uint4*)(XPi + (long)(bb*4096 + rowg)*480 + c*8);
        }
    }
    __syncthreads();

    const float scale1 = 0.17677669529663687f;
    // ---------- two layers of 16-token attention (per-task fused) ----------
#pragma unroll
    for (int l=0; l<2; l++){
        if (l == 1){
#pragma unroll
            for (int i=0;i<4;i++){
                int e = i*256 + tid;
                if (e < 960){
                    int r = e/60, c = e - r*60;
                    int rowg = __shfl(idx1, r);
                    *(uint4*)(XPg + r*XST + c*8) =
                        *(const uint4*)(XPo + (long)(bb*4096 + rowg)*480 + c*8);
                }
            }
            __syncthreads();
        }

        // 5 head-tasks on 4 waves; fused QK->softmax->P->PV, no intra-layer barrier
#pragma unroll
        for (int rep=0; rep<2; rep++){
            int h = w + rep*4;
            if (h < 5){
                bf16x8 ka = *(const bf16x8*)(XPg + ln*XST + 160 + h*32 + g*8);
                bf16x8 qb = *(const bf16x8*)(XPg + ln*XST +       h*32 + g*8);
                f32x4 s = {0.f,0.f,0.f,0.f};
                s = __builtin_amdgcn_mfma_f32_16x16x32_bf16(ka, qb, s, 0,0,0);
                float x[4], m = -1e30f;
#pragma unroll
                for (int r=0;r<4;r++){ x[r] = s[r]*scale1; m = fmaxf(m, x[r]); }
                m = fmaxf(m, __shfl_xor(m, 16));
                m = fmaxf(m, __shfl_xor(m, 32));
                float e0[4], sum = 0.f;
#pragma unroll
                for (int r=0;r<4;r++){ e0[r] = __expf(x[r]-m); sum += e0[r]; }
                sum += __shfl_xor(sum, 16);
                sum += __shfl_xor(sum, 32);
                float inv = 1.f/sum;
                ushort4 pw;
                pw.x = f2bf(e0[0]*inv); pw.y = f2bf(e0[1]*inv);
                pw.z = f2bf(e0[2]*inv); pw.w = f2bf(e0[3]*inv);
                *(ushort4*)(sPh + h*384 + ln*24 + g*4) = pw;

                // PV: same-wave read of sPh[h] (lgkmcnt-ordered)
                u16x8 ta;
#pragma unroll
                for (int jj=0;jj<8;jj++) ta[jj] = 0;
                if (g < 2) ta = *(const u16x8*)(sPh + h*384 + ln*24 + g*8);
                bf16x8 ap = *(bf16x8*)&ta;
#pragma unroll
                for (int half=0; half<2; half++){
                    u16x8 tb;
#pragma unroll
                    for (int jj=0;jj<8;jj++) tb[jj] = 0;
                    if (g < 2){
#pragma unroll
                        for (int jj=0;jj<8;jj++)
                            tb[jj] = XPg[(g*8+jj)*XST + 320 + h*32 + half*16 + ln];
                    }
                    bf16x8 bv = *(bf16x8*)&tb;
                    f32x4 o = {0.f,0.f,0.f,0.f};
                    o = __builtin_amdgcn_mfma_f32_16x16x32_bf16(ap, bv, o, 0,0,0);
#pragma unroll
                    for (int r=0;r<4;r++)
                        sO[(l*16 + g*4+r)*168 + h*32 + half*16 + ln] = f2bf(o[r]);
                }
            }
        }
        __syncthreads();
    }

    // ---------- Phase B: O fragments -> registers ----------
    const int wl = w >> 1, wn = w & 1;
    const ushort* Hw = wl ? Ho  : Hi;
    const float*  cw = wl ? c_o : c_i;

    bf16x8 ofr[5];
#pragma unroll
    for (int kc=0; kc<5; kc++)
        ofr[kc] = *(const bf16x8*)(sO + (wl*16 + ln)*168 + kc*32 + g*8);

    bf16x8 hf[5], hn[5];
#pragma unroll
    for (int kc=0; kc<5; kc++)
        hf[kc] = *(const bf16x8*)(Hw + (long)(wn*16 + ln)*160 + kc*32 + g*8);
    __syncthreads();   // all sO reads done; LDS repurposed below

    ushort* sFQ = lds;              // 32 * 328 = 10496 us
    ushort* sVt = lds + 10496;      // 160 * 40 = 6400 us (ends 16896)
    ushort* sPf = lds + 16896;      // 32 * 40  = 1280 us (ends 18176)

    // ---------- Phase C: FQ^T gemm (30 col-groups on 2 waves/layer) ----------
    for (int t=0; t<15; t++){
        const int cg = t*2 + wn;
        if (t < 14){
            const ushort* hrow = Hw + (long)((cg+2)*16 + ln)*160;
#pragma unroll
            for (int kc=0; kc<5; kc++)
                hn[kc] = *(const bf16x8*)(hrow + kc*32 + g*8);
        }

        f32x4 acc = {0.f,0.f,0.f,0.f};
#pragma unroll
        for (int kc=0; kc<5; kc++)
            acc = __builtin_amdgcn_mfma_f32_16x16x32_bf16(hf[kc], ofr[kc], acc, 0,0,0);

        const int cb0 = cg*16 + g*4;
        float4 cb = *(const float4*)(cw + cb0);
        if (cg < 20){
            ushort4 w4;
            w4.x = f2bf(acc[0] + cb.x);
            w4.y = f2bf(acc[1] + cb.y);
            w4.z = f2bf(acc[2] + cb.z);
            w4.w = f2bf(acc[3] + cb.w);
            *(ushort4*)(sFQ + (wl*16 + ln)*328 + cb0) = w4;
        } else {
            const int c0 = cb0 - 320;
            sVt[(c0+0)*40 + wl*16 + ln] = f2bf(acc[0] + cb.x);
            sVt[(c0+1)*40 + wl*16 + ln] = f2bf(acc[1] + cb.y);
            sVt[(c0+2)*40 + wl*16 + ln] = f2bf(acc[2] + cb.z);
            sVt[(c0+3)*40 + wl*16 + ln] = f2bf(acc[3] + cb.w);
        }
#pragma unroll
        for (int kc=0; kc<5; kc++) hf[kc] = hn[kc];
    }
    __syncthreads();

    // ---------- Phase D: final attention + max-pool (waves 0,1) ----------
    const int th = w;
    if (w < 2){
        f32x4 sc[2];
#pragma unroll
        for (int tj=0; tj<2; tj++){
            f32x4 a = {0.f,0.f,0.f,0.f};
#pragma unroll
            for (int kc=0; kc<5; kc++){
                bf16x8 ka = *(const bf16x8*)(sFQ + (tj*16+ln)*328 + 160 + kc*32 + g*8);
                bf16x8 qb = *(const bf16x8*)(sFQ + (th*16+ln)*328 +       kc*32 + g*8);
                a = __builtin_amdgcn_mfma_f32_16x16x32_bf16(ka, qb, a, 0,0,0);
            }
            sc[tj] = a;
        }

        const float scale = 0.07905694150420949f;
        float x[2][4], m = -1e30f;
#pragma unroll
        for (int tj=0; tj<2; tj++)
#pragma unroll
            for (int r=0;r<4;r++){ x[tj][r] = sc[tj][r]*scale; m = fmaxf(m, x[tj][r]); }
        m = fmaxf(m, __shfl_xor(m, 16));
        m = fmaxf(m, __shfl_xor(m, 32));
        float sum = 0.f;
#pragma unroll
        for (int tj=0; tj<2; tj++)
#pragma unroll
            for (int r=0;r<4;r++){ x[tj][r] = __expf(x[tj][r]-m); sum += x[tj][r]; }
        sum += __shfl_xor(sum, 16);
        sum += __shfl_xor(sum, 32);
        float inv = 1.f/sum;
#pragma unroll
        for (int tj=0; tj<2; tj++){
            ushort4 pw;
            pw.x = f2bf(x[tj][0]*inv); pw.y = f2bf(x[tj][1]*inv);
            pw.z = f2bf(x[tj][2]*inv); pw.w = f2bf(x[tj][3]*inv);
            *(ushort4*)(sPf + (th*16+ln)*40 + tj*16 + g*4) = pw;
        }
    }
    __syncthreads();

    if (w < 2){
        bf16x8 ap[2];
#pragma unroll
        for (int mi=0; mi<2; mi++)
            ap[mi] = *(const bf16x8*)(sPf + (mi*16+ln)*40 + g*8);

#pragma unroll
        for (int nt5=0; nt5<5; nt5++){
            const int nt = th*5 + nt5;
            bf16x8 bv = *(const bf16x8*)(sVt + (nt*16+ln)*40 + g*8);
            float vmax = -1e30f;
            f32x4 o0 = {0.f,0.f,0.f,0.f}, o1 = {0.f,0.f,0.f,0.f};
            o0 = __builtin_amdgcn_mfma_f32_16x16x32_bf16(ap[0], bv, o0, 0,0,0);
            o1 = __builtin_amdgcn_mfma_f32_16x16x32_bf16(ap[1], bv, o1, 0,0,0);
#pragma unroll
            for (int r=0;r<4;r++) vmax = fmaxf(vmax, fmaxf(o0[r], o1[r]));
            vmax = fmaxf(vmax, __shfl_xor(vmax, 16));
            vmax = fmaxf(vmax, __shfl_xor(vmax, 32));
            if (g == 0){
                int col = nt*16 + ln;
                pooled[(long)node*160 + col] = vmax + fb[col];
            }
        }
    }
}

// ============================ host ============================
extern "C" void kernel_launch(void* const* d_in, const int* in_sizes, int n_in,
                              void* d_out, int out_size, void* d_ws, size_t ws_size,
                              hipStream_t stream)
{
    const float* X       = (const float*)d_in[0];
    const int*   in_idx  = (const int*)  d_in[1];
    const int*   out_idx = (const int*)  d_in[2];
    const float* iWq     = (const float*)d_in[3];
    const float* iWk     = (const float*)d_in[4];
    const float* iWv     = (const float*)d_in[5];
    const float* i_in_w  = (const float*)d_in[6];
    const float* i_in_b  = (const float*)d_in[7];
    const float* i_out_w = (const float*)d_in[8];
    const float* i_out_b = (const float*)d_in[9];
    const float* oWq     = (const float*)d_in[10];
    const float* oWk     = (const float*)d_in[11];
    const float* oWv     = (const float*)d_in[12];
    const float* o_in_w  = (const float*)d_in[13];
    const float* o_in_b  = (const float*)d_in[14];
    const float* o_out_w = (const float*)d_in[15];
    const float* o_out_b = (const float*)d_in[16];
    const float* f_in_w  = (const float*)d_in[17];
    const float* f_in_b  = (const float*)d_in[18];
    const float* f_out_w = (const float*)d_in[19];
    const float* f_out_b = (const float*)d_in[20];
    const float* lin_w   = (const float*)d_in[21];
    const float* lin_b   = (const float*)d_in[22];

    float* ws = (float*)d_ws;
    float* pooled = ws;                           // 32768*160 fp32
    float* c_i    = pooled + 5242880;             // 480 (folded)
    float* c_o    = c_i + 480;
    float* cvt_i  = c_o + 480;                    // 480 raw
    float* cvt_o  = cvt_i + 480;
    float* Hvt_i  = cvt_o + 480;                  // 160x160 fp32
    float* Hvt_o  = Hvt_i + 25600;
    ushort* Xb    = (ushort*)(Hvt_o + 25600);     // 32768*160 bf16
    ushort* XPb_i = Xb + 5242880;                 // 32768*480 bf16
    ushort* XPb_o = XPb_i + 15728640;
    ushort* Wci_h = XPb_o + 15728640;             // 76800 each
    ushort* Wco_h = Wci_h + 76800;
    ushort* Hi_h  = Wco_h + 76800;
    ushort* Ho_h  = Hi_h  + 76800;
    ushort* li_h  = Ho_h  + 76800;                // 25600 each
    ushort* li_l  = li_h  + 25600;

    prep_combined_bf<<<300,NTH,0,stream>>>(iWq,iWk,iWv,i_in_w, Wci_h);
    prep_combined_bf<<<300,NTH,0,stream>>>(oWq,oWk,oWv,o_in_w, Wco_h);
    prep_H_split<<<300,NTH,0,stream>>>(f_in_w, i_out_w, Hi_h, Hvt_i);
    prep_H_split<<<300,NTH,0,stream>>>(f_in_w, o_out_w, Ho_h, Hvt_o);
    prep_H_fold<<<100,NTH,0,stream>>>(f_out_w, Hvt_i, Hi_h);
    prep_H_fold<<<100,NTH,0,stream>>>(f_out_w, Hvt_o, Ho_h);
    prep_cvec<<<2,NTH,0,stream>>>(f_in_w, i_out_b, f_in_b, cvt_i);
    prep_cvec<<<2,NTH,0,stream>>>(f_in_w, o_out_b, f_in_b, cvt_o);
    prep_cvec_fold<<<2,NTH,0,stream>>>(f_out_w, cvt_i, c_i);
    prep_cvec_fold<<<2,NTH,0,stream>>>(f_out_w, cvt_o, c_o);
    prep_conv_bf2<<<100,NTH,0,stream>>>(lin_w, li_h, li_l, 25600);
    prep_conv_bf1<<<20480,NTH,0,stream>>>(X, Xb, 5242880);

    // XP = Xb @ Wc^T + in_b  -> bf16 (both layers via z)
    dim3 g1(256, 3, 2);
    gemm_bf<<<g1,NTH,0,stream>>>(Xb, Xb, Wci_h, Wco_h, i_in_b, o_in_b,
                                 XPb_i, XPb_o, 480);

    // everything per-node fused: layer attn x2 + FQ gemm + final attn + pool
    mega_node<<<32768,NTH,0,stream>>>(XPb_i, XPb_o, in_idx, out_idx,
                                      Hi_h, Ho_h, c_i, c_o, f_out_b, pooled);

    // out = ELU(pooled @ lin_w^T + lin_b)  fp32, split-x3
    dim3 g6(256, 1);
    gemm_mfma_lin<<<g6,NTH,0,stream>>>(pooled, li_h, li_l, lin_b, (float*)d_out, 160);
}

// Round 10
// 760.340 us; speedup vs baseline: 1.2462x; 1.2462x over previous
//
#include <hip/hip_runtime.h>
#include <hip/hip_bf16.h>
#include <math.h>

#define NTH 256

typedef __bf16 bf16x8 __attribute__((ext_vector_type(8)));
typedef float  f32x4  __attribute__((ext_vector_type(4)));
typedef unsigned short ushort;
typedef ushort u16x8 __attribute__((ext_vector_type(8)));

// native RNE float->bf16 (v_cvt_pk_bf16_f32); identical rounding to bit-trick
__device__ __forceinline__ ushort f2bf(float x){
    union { __bf16 b; ushort u; } v;
    v.b = (__bf16)x;
    return v.u;
}
__device__ __forceinline__ float bf2f(ushort h){
    union { unsigned int u; float f; } v; v.u = ((unsigned int)h) << 16;
    return v.f;
}

// ============================ prep kernels ============================
__global__ void prep_combined_bf(const float* __restrict__ Wq, const float* __restrict__ Wk,
                                 const float* __restrict__ Wv, const float* __restrict__ in_w,
                                 ushort* __restrict__ dh)
{
    int o = blockIdx.x*NTH + threadIdx.x;
    if (o >= 76800) return;
    int c = o/160, j = o - c*160;
    const float* Wsel = (c<160) ? Wq : (c<320) ? Wk : Wv;
    const float* wrow = Wsel + j*160;
    const float* irow = in_w + c*160;
    float s = 0.f;
    for (int k=0;k<160;k++) s = fmaf(wrow[k], irow[k], s);
    dh[o] = f2bf(s);
}

__global__ void prep_H_split(const float* __restrict__ f_in_w, const float* __restrict__ out_w,
                             ushort* __restrict__ dh, float* __restrict__ tmp)
{
    int o = blockIdx.x*NTH + threadIdx.x;
    if (o >= 76800) return;
    int n = o/160, k = o - n*160;
    float s = 0.f;
    for (int c=0;c<160;c++) s = fmaf(f_in_w[n*160+c], out_w[c*160+k], s);
    if (n < 320) dh[o] = f2bf(s);
    else         tmp[(n-320)*160 + k] = s;
}

__global__ void prep_H_fold(const float* __restrict__ fo, const float* __restrict__ Hv,
                            ushort* __restrict__ dh)
{
    int o = blockIdx.x*NTH + threadIdx.x;
    if (o >= 25600) return;
    int n = o/160, k = o - n*160;
    float s = 0.f;
    for (int j=0;j<160;j++) s = fmaf(fo[n*160+j], Hv[j*160+k], s);
    dh[(320+n)*160 + k] = f2bf(s);
}

__global__ void prep_cvec(const float* __restrict__ f_in_w, const float* __restrict__ out_b,
                          const float* __restrict__ f_in_b, float* __restrict__ cvt)
{
    int n = blockIdx.x*NTH + threadIdx.x;
    if (n >= 480) return;
    float s = f_in_b[n];
    for (int c=0;c<160;c++) s = fmaf(f_in_w[n*160+c], out_b[c], s);
    cvt[n] = s;
}

__global__ void prep_cvec_fold(const float* __restrict__ fo, const float* __restrict__ cvt,
                               float* __restrict__ cv)
{
    int n = blockIdx.x*NTH + threadIdx.x;
    if (n >= 480) return;
    if (n < 320){ cv[n] = cvt[n]; return; }
    int m = n - 320;
    float s = 0.f;
    for (int j=0;j<160;j++) s = fmaf(fo[m*160+j], cvt[320+j], s);
    cv[n] = s;
}

__global__ void prep_conv_bf1(const float* __restrict__ src, ushort* __restrict__ dh, int n)
{
    int o = blockIdx.x*NTH + threadIdx.x;
    if (o >= n) return;
    dh[o] = f2bf(src[o]);
}

__global__ void prep_conv_bf2(const float* __restrict__ src,
                              ushort* __restrict__ dh, ushort* __restrict__ dl, int n)
{
    int o = blockIdx.x*NTH + threadIdx.x;
    if (o >= n) return;
    float s = src[o];
    ushort h = f2bf(s);
    dh[o] = h; dl[o] = f2bf(s - bf2f(h));
}

// ============================ MFMA GEMM (fp32 A, split-x3) — final linear ============
__global__ __launch_bounds__(NTH)
void gemm_mfma_lin(const float* __restrict__ A,
                   const ushort* __restrict__ Wh, const ushort* __restrict__ Wl,
                   const float* __restrict__ bias, float* __restrict__ C, int N)
{
    __shared__ ushort sAh[128*40], sAl[128*40];
    __shared__ ushort sWh[160*40], sWl[160*40];

    const int tid = threadIdx.x;
    const int lane = tid & 63, wave = tid >> 6;
    const int wm = wave >> 1, wn = wave & 1;
    const int ln = lane & 15, g = lane >> 4;
    const long m0 = (long)blockIdx.x * 128;
    const int  n0 = blockIdx.y * 160;

    f32x4 acc[4][5];
#pragma unroll
    for (int mt=0;mt<4;mt++)
#pragma unroll
        for (int nt=0;nt<5;nt++)
#pragma unroll
            for (int r=0;r<4;r++) acc[mt][nt][r] = 0.f;

    for (int k0=0;k0<160;k0+=32){
#pragma unroll
        for (int i=0;i<4;i++){
            int f = tid + 256*i;
            int m = f >> 3, seg = f & 7;
            float4 v = *(const float4*)(A + (m0+m)*160 + k0 + seg*4);
            ushort4 hv, lv;
            hv.x = f2bf(v.x); lv.x = f2bf(v.x - bf2f(hv.x));
            hv.y = f2bf(v.y); lv.y = f2bf(v.y - bf2f(hv.y));
            hv.z = f2bf(v.z); lv.z = f2bf(v.z - bf2f(hv.z));
            hv.w = f2bf(v.w); lv.w = f2bf(v.w - bf2f(hv.w));
            *(ushort4*)(sAh + m*40 + seg*4) = hv;
            *(ushort4*)(sAl + m*40 + seg*4) = lv;
        }
#pragma unroll
        for (int i=0;i<5;i++){
            int e = tid + 256*i;
            int pl = (e >= 640);
            int idx = pl ? e-640 : e;
            int n = idx >> 2, seg = idx & 3;
            const ushort* src = (pl ? Wl : Wh) + (long)(n0+n)*160 + k0 + seg*8;
            ushort* dst = (pl ? sWl : sWh) + n*40 + seg*8;
            *(uint4*)dst = *(const uint4*)src;
        }
        __syncthreads();

        bf16x8 ah[4], al[4];
#pragma unroll
        for (int mt=0;mt<4;mt++){
            int off = (wm*64 + mt*16 + ln)*40 + g*8;
            ah[mt] = *(const bf16x8*)(sAh + off);
            al[mt] = *(const bf16x8*)(sAl + off);
        }
#pragma unroll
        for (int nt=0;nt<5;nt++){
            int offw = (wn*80 + nt*16 + ln)*40 + g*8;
            bf16x8 bh = *(const bf16x8*)(sWh + offw);
            bf16x8 bl = *(const bf16x8*)(sWl + offw);
#pragma unroll
            for (int mt=0;mt<4;mt++){
                acc[mt][nt] = __builtin_amdgcn_mfma_f32_16x16x32_bf16(ah[mt], bh, acc[mt][nt], 0,0,0);
                acc[mt][nt] = __builtin_amdgcn_mfma_f32_16x16x32_bf16(al[mt], bh, acc[mt][nt], 0,0,0);
                acc[mt][nt] = __builtin_amdgcn_mfma_f32_16x16x32_bf16(ah[mt], bl, acc[mt][nt], 0,0,0);
            }
        }
        __syncthreads();
    }

#pragma unroll
    for (int nt=0;nt<5;nt++){
        int col = n0 + wn*80 + nt*16 + ln;
        float bv = bias[col];
#pragma unroll
        for (int mt=0;mt<4;mt++){
#pragma unroll
            for (int r=0;r<4;r++){
                long row = m0 + wm*64 + mt*16 + g*4 + r;
                float x = acc[mt][nt][r] + bv;
                x = x > 0.f ? x : expm1f(x);
                C[row*N + col] = x;
            }
        }
    }
}

// ============================ bf16 GEMM (A bf16, W single-plane) — XP projection ======
__global__ __launch_bounds__(NTH)
void gemm_bf(const ushort* __restrict__ A0, const ushort* __restrict__ A1,
             const ushort* __restrict__ Wh0, const ushort* __restrict__ Wh1,
             const float* __restrict__ b0, const float* __restrict__ b1,
             ushort* __restrict__ C0, ushort* __restrict__ C1, int N)
{
    const int z = blockIdx.z;
    const ushort* A  = z ? A1 : A0;
    const ushort* Wh = z ? Wh1 : Wh0;
    const float* bias = z ? b1 : b0;
    ushort* C = z ? C1 : C0;

    __shared__ ushort sA[128*40];
    __shared__ ushort sW[160*40];

    const int tid = threadIdx.x;
    const int lane = tid & 63, wave = tid >> 6;
    const int wm = wave >> 1, wn = wave & 1;
    const int ln = lane & 15, g = lane >> 4;
    const long m0 = (long)blockIdx.x * 128;
    const int  n0 = blockIdx.y * 160;

    f32x4 acc[4][5];
#pragma unroll
    for (int mt=0;mt<4;mt++)
#pragma unroll
        for (int nt=0;nt<5;nt++)
#pragma unroll
            for (int r=0;r<4;r++) acc[mt][nt][r] = 0.f;

    for (int k0=0;k0<160;k0+=32){
#pragma unroll
        for (int i=0;i<2;i++){
            int e = tid + 256*i;
            int m = e >> 2, seg = e & 3;
            *(uint4*)(sA + m*40 + seg*8) =
                *(const uint4*)(A + (m0+m)*160 + k0 + seg*8);
        }
#pragma unroll
        for (int i=0;i<3;i++){
            int e = tid + 256*i;
            if (e < 640){
                int n = e >> 2, seg = e & 3;
                *(uint4*)(sW + n*40 + seg*8) =
                    *(const uint4*)(Wh + (long)(n0+n)*160 + k0 + seg*8);
            }
        }
        __syncthreads();

        bf16x8 af[4];
#pragma unroll
        for (int mt=0;mt<4;mt++)
            af[mt] = *(const bf16x8*)(sA + (wm*64 + mt*16 + ln)*40 + g*8);
#pragma unroll
        for (int nt=0;nt<5;nt++){
            bf16x8 bh = *(const bf16x8*)(sW + (wn*80 + nt*16 + ln)*40 + g*8);
#pragma unroll
            for (int mt=0;mt<4;mt++)
                acc[mt][nt] = __builtin_amdgcn_mfma_f32_16x16x32_bf16(af[mt], bh, acc[mt][nt], 0,0,0);
        }
        __syncthreads();
    }

#pragma unroll
    for (int nt=0;nt<5;nt++){
        int col = n0 + wn*80 + nt*16 + ln;
        float bv = bias[col];
#pragma unroll
        for (int mt=0;mt<4;mt++){
#pragma unroll
            for (int r=0;r<4;r++){
                long row = m0 + wm*64 + mt*16 + g*4 + r;
                C[row*N + col] = f2bf(acc[mt][nt][r] + bv);
            }
        }
    }
}

// ============================ MFMA attention, layers 1/2 ============
// ROUND-10 redesign: Q/K fragments live in REGISTERS (each lane only ever reads
// its own row ln at column chunk g — LDS was never needed for them). Only V
// (cols 320..479) + Pall stay in LDS: 9088 B/block vs 19712 B -> ~16 blocks/CU
// (4 waves/SIMD) instead of 8 on this gather-latency-bound kernel. V stride 164
// de-aliases the PV scalar-read bank pattern (g-groups hit distinct banks).
__global__ __launch_bounds__(64)
void attn_layer_mfma(const ushort* __restrict__ XPi, const ushort* __restrict__ XPo,
                     const int* __restrict__ in_idx, const int* __restrict__ out_idx,
                     ushort* __restrict__ Oi, ushort* __restrict__ Oo, int node_base)
{
    const ushort* XP = blockIdx.y ? XPo : XPi;
    const int*  idx  = blockIdx.y ? out_idx : in_idx;
    ushort* O        = blockIdx.y ? Oo : Oi;

    __shared__ ushort sV[16*164];     // V cols 320..479, stride 164
    __shared__ ushort Pall[5*16*24];

    const int lane = threadIdx.x;
    const int ln = lane & 15, g = lane >> 4;
    const int node = node_base + blockIdx.x;
    const int bb = node >> 12, nn = node & 4095;

    int idxv = nn;
    if (lane >= 1 && lane < 16) idxv = idx[(long)node*15 + lane-1];

    // per-lane Q/K fragments straight from global: row = shfl(idxv, ln)
    int rowg = __shfl(idxv, ln);
    const ushort* rbase = XP + (long)(bb*4096 + rowg)*480;
    bf16x8 qf[5], kf[5];
#pragma unroll
    for (int h=0;h<5;h++){
        qf[h] = *(const bf16x8*)(rbase +       h*32 + g*8);
        kf[h] = *(const bf16x8*)(rbase + 160 + h*32 + g*8);
    }

    // stage V into LDS: 16 rows x 20 uint4-equivalents (2x ushort4 for 164-stride)
#pragma unroll
    for (int i=0;i<5;i++){
        int e = i*64 + lane;                  // 0..319
        int r = e/20, c = e - r*20;
        int rg = __shfl(idxv, r);
        const ushort* src = XP + (long)(bb*4096 + rg)*480 + 320 + c*8;
        ushort4 v0 = *(const ushort4*)src;
        ushort4 v1 = *(const ushort4*)(src + 4);
        *(ushort4*)(sV + r*164 + c*8)     = v0;
        *(ushort4*)(sV + r*164 + c*8 + 4) = v1;
    }
    __syncthreads();

    const float scale = 0.17677669529663687f;
#pragma unroll
    for (int h=0;h<5;h++){
        f32x4 s = {0.f,0.f,0.f,0.f};
        s = __builtin_amdgcn_mfma_f32_16x16x32_bf16(kf[h], qf[h], s, 0,0,0);
        float x[4], m = -1e30f;
#pragma unroll
        for (int r=0;r<4;r++){ x[r] = s[r]*scale; m = fmaxf(m, x[r]); }
        m = fmaxf(m, __shfl_xor(m, 16));
        m = fmaxf(m, __shfl_xor(m, 32));
        float e0[4], sum = 0.f;
#pragma unroll
        for (int r=0;r<4;r++){ e0[r] = __expf(x[r]-m); sum += e0[r]; }
        sum += __shfl_xor(sum, 16);
        sum += __shfl_xor(sum, 32);
        float inv = 1.f/sum;
        ushort4 pw;
        pw.x = f2bf(e0[0]*inv); pw.y = f2bf(e0[1]*inv);
        pw.z = f2bf(e0[2]*inv); pw.w = f2bf(e0[3]*inv);
        *(ushort4*)(Pall + h*384 + ln*24 + g*4) = pw;
    }
    __syncthreads();

#pragma unroll
    for (int h=0;h<5;h++){
        u16x8 ta;
#pragma unroll
        for (int jj=0;jj<8;jj++) ta[jj] = 0;
        if (g < 2) ta = *(const u16x8*)(Pall + h*384 + ln*24 + g*8);
        bf16x8 ap = *(bf16x8*)&ta;
#pragma unroll
        for (int half=0; half<2; half++){
            u16x8 tb;
#pragma unroll
            for (int jj=0;jj<8;jj++) tb[jj] = 0;
            if (g < 2){
#pragma unroll
                for (int jj=0;jj<8;jj++)
                    tb[jj] = sV[(g*8+jj)*164 + h*32 + half*16 + ln];
            }
            bf16x8 bv = *(bf16x8*)&tb;
            f32x4 o = {0.f,0.f,0.f,0.f};
            o = __builtin_amdgcn_mfma_f32_16x16x32_bf16(ap, bv, o, 0,0,0);
#pragma unroll
            for (int r=0;r<4;r++)
                O[(long)(blockIdx.x*16 + g*4 + r)*160 + h*32 + half*16 + ln] = f2bf(o[r]);
        }
    }
}

// ============================ FUSED: FQ-gemm + final attention + max-pool ============
// (round-2 proven version: 4 nodes / 512 threads / 8 waves, measured 187 us)
__global__ __launch_bounds__(512)
void fused_fq_attn_pool(const ushort* __restrict__ O_i, const ushort* __restrict__ O_o,
                        const ushort* __restrict__ Hi, const ushort* __restrict__ Ho,
                        const float* __restrict__ c_i, const float* __restrict__ c_o,
                        const float* __restrict__ fb, float* __restrict__ pooled,
                        int node_base)
{
    __shared__ ushort sFQ[4*32*328];
    __shared__ ushort sVt[4*160*40];
    __shared__ ushort sP [4*32*40];

    const int tid  = threadIdx.x;
    const int lane = tid & 63, wave = tid >> 6;
    const int ln = lane & 15, g = lane >> 4;
    const int wl = wave >> 2, wn = wave & 3;
    const int nl0 = blockIdx.x * 4;

    const ushort* Ow = wl ? O_o : O_i;
    const ushort* Hw = wl ? Ho  : Hi;
    const float*  cw = wl ? c_o : c_i;

    bf16x8 ofr[4][5];
#pragma unroll
    for (int nd=0; nd<4; nd++)
#pragma unroll
        for (int kc=0; kc<5; kc++)
            ofr[nd][kc] = *(const bf16x8*)(Ow + ((long)(nl0+nd)*16 + ln)*160 + kc*32 + g*8);

    bf16x8 hf[5], hn[5];
#pragma unroll
    for (int kc=0; kc<5; kc++)
        hf[kc] = *(const bf16x8*)(Hw + (long)(wn*16 + ln)*160 + kc*32 + g*8);

    for (int t=0; t<8; t++){
        const int cg  = t*4 + wn;
        const int cgn = cg + 4;
        if (t < 7 && cgn < 30){
            const ushort* hrow = Hw + (long)(cgn*16 + ln)*160;
#pragma unroll
            for (int kc=0; kc<5; kc++)
                hn[kc] = *(const bf16x8*)(hrow + kc*32 + g*8);
        }

        if (cg < 30){
            f32x4 acc[4];
#pragma unroll
            for (int nd=0; nd<4; nd++)
#pragma unroll
                for (int r=0;r<4;r++) acc[nd][r] = 0.f;

#pragma unroll
            for (int kc=0; kc<5; kc++)
#pragma unroll
                for (int nd=0; nd<4; nd++)
                    acc[nd] = __builtin_amdgcn_mfma_f32_16x16x32_bf16(hf[kc], ofr[nd][kc], acc[nd], 0,0,0);

            const int cb0 = cg*16 + g*4;
            float4 cb = *(const float4*)(cw + cb0);
            if (cg < 20){
#pragma unroll
                for (int nd=0; nd<4; nd++){
                    ushort4 w4;
                    w4.x = f2bf(acc[nd][0] + cb.x);
                    w4.y = f2bf(acc[nd][1] + cb.y);
                    w4.z = f2bf(acc[nd][2] + cb.z);
                    w4.w = f2bf(acc[nd][3] + cb.w);
                    *(ushort4*)(sFQ + nd*10496 + (wl*16 + ln)*328 + cb0) = w4;
                }
            } else {
                const int c0 = cb0 - 320;
#pragma unroll
                for (int nd=0; nd<4; nd++){
                    sVt[nd*6400 + (c0+0)*40 + wl*16 + ln] = f2bf(acc[nd][0] + cb.x);
                    sVt[nd*6400 + (c0+1)*40 + wl*16 + ln] = f2bf(acc[nd][1] + cb.y);
                    sVt[nd*6400 + (c0+2)*40 + wl*16 + ln] = f2bf(acc[nd][2] + cb.z);
                    sVt[nd*6400 + (c0+3)*40 + wl*16 + ln] = f2bf(acc[nd][3] + cb.w);
                }
            }
        }
#pragma unroll
        for (int kc=0; kc<5; kc++) hf[kc] = hn[kc];
    }
    __syncthreads();

    const int nd = wave >> 1, th = wave & 1;
    const ushort* myQ = sFQ + nd*10496;
    const ushort* myV = sVt + nd*6400;
    ushort*       myP = sP  + nd*1280;

    f32x4 sc[2];
#pragma unroll
    for (int tj=0; tj<2; tj++){
        f32x4 a = {0.f,0.f,0.f,0.f};
#pragma unroll
        for (int kc=0; kc<5; kc++){
            bf16x8 ka = *(const bf16x8*)(myQ + (tj*16+ln)*328 + 160 + kc*32 + g*8);
            bf16x8 qb = *(const bf16x8*)(myQ + (th*16+ln)*328 +       kc*32 + g*8);
            a = __builtin_amdgcn_mfma_f32_16x16x32_bf16(ka, qb, a, 0,0,0);
        }
        sc[tj] = a;
    }

    const float scale = 0.07905694150420949f;
    {
        float x[2][4], m = -1e30f;
#pragma unroll
        for (int tj=0; tj<2; tj++)
#pragma unroll
            for (int r=0;r<4;r++){ x[tj][r] = sc[tj][r]*scale; m = fmaxf(m, x[tj][r]); }
        m = fmaxf(m, __shfl_xor(m, 16));
        m = fmaxf(m, __shfl_xor(m, 32));
        float sum = 0.f;
#pragma unroll
        for (int tj=0; tj<2; tj++)
#pragma unroll
            for (int r=0;r<4;r++){ x[tj][r] = __expf(x[tj][r]-m); sum += x[tj][r]; }
        sum += __shfl_xor(sum, 16);
        sum += __shfl_xor(sum, 32);
        float inv = 1.f/sum;
#pragma unroll
        for (int tj=0; tj<2; tj++){
            ushort4 pw;
            pw.x = f2bf(x[tj][0]*inv); pw.y = f2bf(x[tj][1]*inv);
            pw.z = f2bf(x[tj][2]*inv); pw.w = f2bf(x[tj][3]*inv);
            *(ushort4*)(myP + (th*16+ln)*40 + tj*16 + g*4) = pw;
        }
    }
    __syncthreads();

    bf16x8 ap[2];
#pragma unroll
    for (int mi=0; mi<2; mi++)
        ap[mi] = *(const bf16x8*)(myP + (mi*16+ln)*40 + g*8);

    const long node = (long)node_base + nl0 + nd;
#pragma unroll
    for (int nt5=0; nt5<5; nt5++){
        const int nt = th*5 + nt5;
        bf16x8 bv = *(const bf16x8*)(myV + (nt*16+ln)*40 + g*8);
        float vmax = -1e30f;
#pragma unroll
        for (int mi=0; mi<2; mi++){
            f32x4 o = {0.f,0.f,0.f,0.f};
            o = __builtin_amdgcn_mfma_f32_16x16x32_bf16(ap[mi], bv, o, 0,0,0);
#pragma unroll
            for (int r=0;r<4;r++) vmax = fmaxf(vmax, o[r]);
        }
        vmax = fmaxf(vmax, __shfl_xor(vmax, 16));
        vmax = fmaxf(vmax, __shfl_xor(vmax, 32));
        if (g == 0){
            int col = nt*16 + ln;
            pooled[node*160 + col] = vmax + fb[col];
        }
    }
}

// ============================ host ============================
extern "C" void kernel_launch(void* const* d_in, const int* in_sizes, int n_in,
                              void* d_out, int out_size, void* d_ws, size_t ws_size,
                              hipStream_t stream)
{
    const float* X       = (const float*)d_in[0];
    const int*   in_idx  = (const int*)  d_in[1];
    const int*   out_idx = (const int*)  d_in[2];
    const float* iWq     = (const float*)d_in[3];
    const float* iWk     = (const float*)d_in[4];
    const float* iWv     = (const float*)d_in[5];
    const float* i_in_w  = (const float*)d_in[6];
    const float* i_in_b  = (const float*)d_in[7];
    const float* i_out_w = (const float*)d_in[8];
    const float* i_out_b = (const float*)d_in[9];
    const float* oWq     = (const float*)d_in[10];
    const float* oWk     = (const float*)d_in[11];
    const float* oWv     = (const float*)d_in[12];
    const float* o_in_w  = (const float*)d_in[13];
    const float* o_in_b  = (const float*)d_in[14];
    const float* o_out_w = (const float*)d_in[15];
    const float* o_out_b = (const float*)d_in[16];
    const float* f_in_w  = (const float*)d_in[17];
    const float* f_in_b  = (const float*)d_in[18];
    const float* f_out_w = (const float*)d_in[19];
    const float* f_out_b = (const float*)d_in[20];
    const float* lin_w   = (const float*)d_in[21];
    const float* lin_b   = (const float*)d_in[22];

    float* ws = (float*)d_ws;
    float* pooled = ws;                           // 32768*160 fp32
    float* c_i    = pooled + 5242880;             // 480 (folded)
    float* c_o    = c_i + 480;
    float* cvt_i  = c_o + 480;                    // 480 raw
    float* cvt_o  = cvt_i + 480;
    float* Hvt_i  = cvt_o + 480;                  // 160x160 fp32
    float* Hvt_o  = Hvt_i + 25600;
    ushort* ub    = (ushort*)(Hvt_o + 25600);
    ushort* Xb    = ub;                           // 32768*160 bf16
    ushort* XPb_i = Xb + 5242880;                 // 32768*480 bf16
    ushort* XPb_o = XPb_i + 15728640;
    ushort* Wci_h = XPb_o + 15728640;             // 76800 each
    ushort* Wco_h = Wci_h + 76800;
    ushort* Hi_h  = Wco_h + 76800;
    ushort* Ho_h  = Hi_h  + 76800;
    ushort* li_h  = Ho_h  + 76800;                // 25600 each
    ushort* li_l  = li_h  + 25600;
    ushort* sb_us = li_l + 25600;
    const unsigned long long fixed = 23825280ULL; // floats

    size_t avail = ws_size / 4;
    int ns = 32768;
    while (ns > 64 && fixed + 2560ULL*ns > avail) ns >>= 1;

    ushort* O_i = sb_us;                          // ns*16*160
    ushort* O_o = O_i + (size_t)2560*ns;

    prep_combined_bf<<<300,NTH,0,stream>>>(iWq,iWk,iWv,i_in_w, Wci_h);
    prep_combined_bf<<<300,NTH,0,stream>>>(oWq,oWk,oWv,o_in_w, Wco_h);
    prep_H_split<<<300,NTH,0,stream>>>(f_in_w, i_out_w, Hi_h, Hvt_i);
    prep_H_split<<<300,NTH,0,stream>>>(f_in_w, o_out_w, Ho_h, Hvt_o);
    prep_H_fold<<<100,NTH,0,stream>>>(f_out_w, Hvt_i, Hi_h);
    prep_H_fold<<<100,NTH,0,stream>>>(f_out_w, Hvt_o, Ho_h);
    prep_cvec<<<2,NTH,0,stream>>>(f_in_w, i_out_b, f_in_b, cvt_i);
    prep_cvec<<<2,NTH,0,stream>>>(f_in_w, o_out_b, f_in_b, cvt_o);
    prep_cvec_fold<<<2,NTH,0,stream>>>(f_out_w, cvt_i, c_i);
    prep_cvec_fold<<<2,NTH,0,stream>>>(f_out_w, cvt_o, c_o);
    prep_conv_bf2<<<100,NTH,0,stream>>>(lin_w, li_h, li_l, 25600);
    prep_conv_bf1<<<20480,NTH,0,stream>>>(X, Xb, 5242880);

    // XP = Xb @ Wc^T + in_b  -> bf16 (both layers via z)
    dim3 g1(256, 3, 2);
    gemm_bf<<<g1,NTH,0,stream>>>(Xb, Xb, Wci_h, Wco_h, i_in_b, o_in_b,
                                 XPb_i, XPb_o, 480);

    int S = 32768 / ns;
    for (int s=0;s<S;s++){
        int base = s*ns;
        dim3 ga(ns, 2);
        attn_layer_mfma<<<ga,64,0,stream>>>(XPb_i, XPb_o, in_idx, out_idx, O_i, O_o, base);
        fused_fq_attn_pool<<<ns/4,512,0,stream>>>(O_i, O_o, Hi_h, Ho_h, c_i, c_o,
                                                  f_out_b, pooled, base);
    }

    // out = ELU(pooled @ lin_w^T + lin_b)  fp32, split-x3
    dim3 g6(256, 1);
    gemm_mfma_lin<<<g6,NTH,0,stream>>>(pooled, li_h, li_l, lin_b, (float*)d_out, 160);
}

// Round 12
// 754.918 us; speedup vs baseline: 1.2551x; 1.0072x over previous
//
#include <hip/hip_runtime.h>
#include <hip/hip_bf16.h>
#include <math.h>

#define NTH 256

typedef __bf16 bf16x8 __attribute__((ext_vector_type(8)));
typedef float  f32x4  __attribute__((ext_vector_type(4)));
typedef unsigned short ushort;
typedef ushort u16x8 __attribute__((ext_vector_type(8)));

// native RNE float->bf16 (v_cvt_pk_bf16_f32); identical rounding to bit-trick
__device__ __forceinline__ ushort f2bf(float x){
    union { __bf16 b; ushort u; } v;
    v.b = (__bf16)x;
    return v.u;
}
__device__ __forceinline__ float bf2f(ushort h){
    union { unsigned int u; float f; } v; v.u = ((unsigned int)h) << 16;
    return v.f;
}

// ============================ prep kernels ============================
__global__ void prep_combined_bf(const float* __restrict__ Wq, const float* __restrict__ Wk,
                                 const float* __restrict__ Wv, const float* __restrict__ in_w,
                                 ushort* __restrict__ dh)
{
    int o = blockIdx.x*NTH + threadIdx.x;
    if (o >= 76800) return;
    int c = o/160, j = o - c*160;
    const float* Wsel = (c<160) ? Wq : (c<320) ? Wk : Wv;
    const float* wrow = Wsel + j*160;
    const float* irow = in_w + c*160;
    float s = 0.f;
    for (int k=0;k<160;k++) s = fmaf(wrow[k], irow[k], s);
    dh[o] = f2bf(s);
}

__global__ void prep_H_split(const float* __restrict__ f_in_w, const float* __restrict__ out_w,
                             ushort* __restrict__ dh, float* __restrict__ tmp)
{
    int o = blockIdx.x*NTH + threadIdx.x;
    if (o >= 76800) return;
    int n = o/160, k = o - n*160;
    float s = 0.f;
    for (int c=0;c<160;c++) s = fmaf(f_in_w[n*160+c], out_w[c*160+k], s);
    if (n < 320) dh[o] = f2bf(s);
    else         tmp[(n-320)*160 + k] = s;
}

__global__ void prep_H_fold(const float* __restrict__ fo, const float* __restrict__ Hv,
                            ushort* __restrict__ dh)
{
    int o = blockIdx.x*NTH + threadIdx.x;
    if (o >= 25600) return;
    int n = o/160, k = o - n*160;
    float s = 0.f;
    for (int j=0;j<160;j++) s = fmaf(fo[n*160+j], Hv[j*160+k], s);
    dh[(320+n)*160 + k] = f2bf(s);
}

__global__ void prep_cvec(const float* __restrict__ f_in_w, const float* __restrict__ out_b,
                          const float* __restrict__ f_in_b, float* __restrict__ cvt)
{
    int n = blockIdx.x*NTH + threadIdx.x;
    if (n >= 480) return;
    float s = f_in_b[n];
    for (int c=0;c<160;c++) s = fmaf(f_in_w[n*160+c], out_b[c], s);
    cvt[n] = s;
}

__global__ void prep_cvec_fold(const float* __restrict__ fo, const float* __restrict__ cvt,
                               float* __restrict__ cv)
{
    int n = blockIdx.x*NTH + threadIdx.x;
    if (n >= 480) return;
    if (n < 320){ cv[n] = cvt[n]; return; }
    int m = n - 320;
    float s = 0.f;
    for (int j=0;j<160;j++) s = fmaf(fo[m*160+j], cvt[320+j], s);
    cv[n] = s;
}

__global__ void prep_conv_bf1(const float* __restrict__ src, ushort* __restrict__ dh, int n)
{
    int o = blockIdx.x*NTH + threadIdx.x;
    if (o >= n) return;
    dh[o] = f2bf(src[o]);
}

__global__ void prep_conv_bf2(const float* __restrict__ src,
                              ushort* __restrict__ dh, ushort* __restrict__ dl, int n)
{
    int o = blockIdx.x*NTH + threadIdx.x;
    if (o >= n) return;
    float s = src[o];
    ushort h = f2bf(s);
    dh[o] = h; dl[o] = f2bf(s - bf2f(h));
}

// ============================ MFMA GEMM (fp32 A, split-x3) — final linear ============
__global__ __launch_bounds__(NTH)
void gemm_mfma_lin(const float* __restrict__ A,
                   const ushort* __restrict__ Wh, const ushort* __restrict__ Wl,
                   const float* __restrict__ bias, float* __restrict__ C, int N)
{
    __shared__ ushort sAh[128*40], sAl[128*40];
    __shared__ ushort sWh[160*40], sWl[160*40];

    const int tid = threadIdx.x;
    const int lane = tid & 63, wave = tid >> 6;
    const int wm = wave >> 1, wn = wave & 1;
    const int ln = lane & 15, g = lane >> 4;
    const long m0 = (long)blockIdx.x * 128;
    const int  n0 = blockIdx.y * 160;

    f32x4 acc[4][5];
#pragma unroll
    for (int mt=0;mt<4;mt++)
#pragma unroll
        for (int nt=0;nt<5;nt++)
#pragma unroll
            for (int r=0;r<4;r++) acc[mt][nt][r] = 0.f;

    for (int k0=0;k0<160;k0+=32){
#pragma unroll
        for (int i=0;i<4;i++){
            int f = tid + 256*i;
            int m = f >> 3, seg = f & 7;
            float4 v = *(const float4*)(A + (m0+m)*160 + k0 + seg*4);
            ushort4 hv, lv;
            hv.x = f2bf(v.x); lv.x = f2bf(v.x - bf2f(hv.x));
            hv.y = f2bf(v.y); lv.y = f2bf(v.y - bf2f(hv.y));
            hv.z = f2bf(v.z); lv.z = f2bf(v.z - bf2f(hv.z));
            hv.w = f2bf(v.w); lv.w = f2bf(v.w - bf2f(hv.w));
            *(ushort4*)(sAh + m*40 + seg*4) = hv;
            *(ushort4*)(sAl + m*40 + seg*4) = lv;
        }
#pragma unroll
        for (int i=0;i<5;i++){
            int e = tid + 256*i;
            int pl = (e >= 640);
            int idx = pl ? e-640 : e;
            int n = idx >> 2, seg = idx & 3;
            const ushort* src = (pl ? Wl : Wh) + (long)(n0+n)*160 + k0 + seg*8;
            ushort* dst = (pl ? sWl : sWh) + n*40 + seg*8;
            *(uint4*)dst = *(const uint4*)src;
        }
        __syncthreads();

        bf16x8 ah[4], al[4];
#pragma unroll
        for (int mt=0;mt<4;mt++){
            int off = (wm*64 + mt*16 + ln)*40 + g*8;
            ah[mt] = *(const bf16x8*)(sAh + off);
            al[mt] = *(const bf16x8*)(sAl + off);
        }
#pragma unroll
        for (int nt=0;nt<5;nt++){
            int offw = (wn*80 + nt*16 + ln)*40 + g*8;
            bf16x8 bh = *(const bf16x8*)(sWh + offw);
            bf16x8 bl = *(const bf16x8*)(sWl + offw);
#pragma unroll
            for (int mt=0;mt<4;mt++){
                acc[mt][nt] = __builtin_amdgcn_mfma_f32_16x16x32_bf16(ah[mt], bh, acc[mt][nt], 0,0,0);
                acc[mt][nt] = __builtin_amdgcn_mfma_f32_16x16x32_bf16(al[mt], bh, acc[mt][nt], 0,0,0);
                acc[mt][nt] = __builtin_amdgcn_mfma_f32_16x16x32_bf16(ah[mt], bl, acc[mt][nt], 0,0,0);
            }
        }
        __syncthreads();
    }

#pragma unroll
    for (int nt=0;nt<5;nt++){
        int col = n0 + wn*80 + nt*16 + ln;
        float bv = bias[col];
#pragma unroll
        for (int mt=0;mt<4;mt++){
#pragma unroll
            for (int r=0;r<4;r++){
                long row = m0 + wm*64 + mt*16 + g*4 + r;
                float x = acc[mt][nt][r] + bv;
                x = x > 0.f ? x : expm1f(x);
                C[row*N + col] = x;
            }
        }
    }
}

// ============================ bf16 GEMM (A bf16, W single-plane) — XP projection ======
__global__ __launch_bounds__(NTH)
void gemm_bf(const ushort* __restrict__ A0, const ushort* __restrict__ A1,
             const ushort* __restrict__ Wh0, const ushort* __restrict__ Wh1,
             const float* __restrict__ b0, const float* __restrict__ b1,
             ushort* __restrict__ C0, ushort* __restrict__ C1, int N)
{
    const int z = blockIdx.z;
    const ushort* A  = z ? A1 : A0;
    const ushort* Wh = z ? Wh1 : Wh0;
    const float* bias = z ? b1 : b0;
    ushort* C = z ? C1 : C0;

    __shared__ ushort sA[128*40];
    __shared__ ushort sW[160*40];

    const int tid = threadIdx.x;
    const int lane = tid & 63, wave = tid >> 6;
    const int wm = wave >> 1, wn = wave & 1;
    const int ln = lane & 15, g = lane >> 4;
    const long m0 = (long)blockIdx.x * 128;
    const int  n0 = blockIdx.y * 160;

    f32x4 acc[4][5];
#pragma unroll
    for (int mt=0;mt<4;mt++)
#pragma unroll
        for (int nt=0;nt<5;nt++)
#pragma unroll
            for (int r=0;r<4;r++) acc[mt][nt][r] = 0.f;

    for (int k0=0;k0<160;k0+=32){
#pragma unroll
        for (int i=0;i<2;i++){
            int e = tid + 256*i;
            int m = e >> 2, seg = e & 3;
            *(uint4*)(sA + m*40 + seg*8) =
                *(const uint4*)(A + (m0+m)*160 + k0 + seg*8);
        }
#pragma unroll
        for (int i=0;i<3;i++){
            int e = tid + 256*i;
            if (e < 640){
                int n = e >> 2, seg = e & 3;
                *(uint4*)(sW + n*40 + seg*8) =
                    *(const uint4*)(Wh + (long)(n0+n)*160 + k0 + seg*8);
            }
        }
        __syncthreads();

        bf16x8 af[4];
#pragma unroll
        for (int mt=0;mt<4;mt++)
            af[mt] = *(const bf16x8*)(sA + (wm*64 + mt*16 + ln)*40 + g*8);
#pragma unroll
        for (int nt=0;nt<5;nt++){
            bf16x8 bh = *(const bf16x8*)(sW + (wn*80 + nt*16 + ln)*40 + g*8);
#pragma unroll
            for (int mt=0;mt<4;mt++)
                acc[mt][nt] = __builtin_amdgcn_mfma_f32_16x16x32_bf16(af[mt], bh, acc[mt][nt], 0,0,0);
        }
        __syncthreads();
    }

#pragma unroll
    for (int nt=0;nt<5;nt++){
        int col = n0 + wn*80 + nt*16 + ln;
        float bv = bias[col];
#pragma unroll
        for (int mt=0;mt<4;mt++){
#pragma unroll
            for (int r=0;r<4;r++){
                long row = m0 + wm*64 + mt*16 + g*4 + r;
                C[row*N + col] = f2bf(acc[mt][nt][r] + bv);
            }
        }
    }
}

// ============================ MFMA attention, layers 1/2 ============
// ROUND-12: round-11 structure (4 waves/node, distributed tasks, 1 barrier)
// with the V-staging bug fixed: each e<320 chunk is 8 ushorts (16 B) — round
// 11 copied only ONE ushort4 (4 ushorts), leaving half of sV uninitialized
// (absmax 2.4e30). Two-ushort4 copy restored (stride 164 is only 8B-aligned,
// so a single uint4 LDS write is not safe).
__global__ __launch_bounds__(NTH)
void attn_layer_mfma(const ushort* __restrict__ XPi, const ushort* __restrict__ XPo,
                     const int* __restrict__ in_idx, const int* __restrict__ out_idx,
                     ushort* __restrict__ Oi, ushort* __restrict__ Oo, int node_base)
{
    const ushort* XP = blockIdx.y ? XPo : XPi;
    const int*  idx  = blockIdx.y ? out_idx : in_idx;
    ushort* O        = blockIdx.y ? Oo : Oi;

    __shared__ ushort sV[16*164];     // V cols 320..479, row-major, stride 164
    __shared__ ushort Pall[5*16*24];

    const int tid  = threadIdx.x;
    const int lane = tid & 63, w = tid >> 6;
    const int ln = lane & 15, g = lane >> 4;
    const int node = node_base + blockIdx.x;
    const int bb = node >> 12, nn = node & 4095;

    int idxv = nn;
    if (lane >= 1 && lane < 16) idxv = idx[(long)node*15 + lane-1];
    const ushort* XPbase = XP + (long)bb*4096*480;

    // ---- V staging: 320 chunks of 8 ushorts (16 B) split across 256 threads ----
#pragma unroll
    for (int i=0;i<2;i++){
        int e = i*256 + tid;
        if (e < 320){
            int r = e/20, c = e - r*20;
            int rg = __shfl(idxv, r);
            const ushort* src = XPbase + (long)rg*480 + 320 + c*8;
            ushort4 v0 = *(const ushort4*)src;
            ushort4 v1 = *(const ushort4*)(src + 4);
            *(ushort4*)(sV + r*164 + c*8)     = v0;
            *(ushort4*)(sV + r*164 + c*8 + 4) = v1;
        }
    }

    // ---- QK^T + softmax head-tasks (5 on 4 waves), overlaps V-stage ----
    const float scale = 0.17677669529663687f;
    const int rowg = __shfl(idxv, ln);
    const ushort* rbase = XPbase + (long)rowg*480;
#pragma unroll
    for (int rep=0; rep<2; rep++){
        int h = w + rep*4;
        if (h < 5){
            bf16x8 qb = *(const bf16x8*)(rbase +       h*32 + g*8);
            bf16x8 ka = *(const bf16x8*)(rbase + 160 + h*32 + g*8);
            f32x4 s = {0.f,0.f,0.f,0.f};
            s = __builtin_amdgcn_mfma_f32_16x16x32_bf16(ka, qb, s, 0,0,0);
            float x[4], m = -1e30f;
#pragma unroll
            for (int r=0;r<4;r++){ x[r] = s[r]*scale; m = fmaxf(m, x[r]); }
            m = fmaxf(m, __shfl_xor(m, 16));
            m = fmaxf(m, __shfl_xor(m, 32));
            float e0[4], sum = 0.f;
#pragma unroll
            for (int r=0;r<4;r++){ e0[r] = __expf(x[r]-m); sum += e0[r]; }
            sum += __shfl_xor(sum, 16);
            sum += __shfl_xor(sum, 32);
            float inv = 1.f/sum;
            ushort4 pw;
            pw.x = f2bf(e0[0]*inv); pw.y = f2bf(e0[1]*inv);
            pw.z = f2bf(e0[2]*inv); pw.w = f2bf(e0[3]*inv);
            *(ushort4*)(Pall + h*384 + ln*24 + g*4) = pw;
        }
    }
    __syncthreads();

    // ---- PV tasks: 10 (h x half) on 4 waves ----
#pragma unroll
    for (int rep=0; rep<3; rep++){
        int t = w + rep*4;
        if (t < 10){
            int h = t >> 1, half = t & 1;
            u16x8 ta;
#pragma unroll
            for (int jj=0;jj<8;jj++) ta[jj] = 0;
            if (g < 2) ta = *(const u16x8*)(Pall + h*384 + ln*24 + g*8);
            bf16x8 ap = *(bf16x8*)&ta;

            u16x8 tb;
#pragma unroll
            for (int jj=0;jj<8;jj++) tb[jj] = 0;
            if (g < 2){
#pragma unroll
                for (int jj=0;jj<8;jj++)
                    tb[jj] = sV[(g*8+jj)*164 + h*32 + half*16 + ln];
            }
            bf16x8 bv = *(bf16x8*)&tb;
            f32x4 o = {0.f,0.f,0.f,0.f};
            o = __builtin_amdgcn_mfma_f32_16x16x32_bf16(ap, bv, o, 0,0,0);
#pragma unroll
            for (int r=0;r<4;r++)
                O[(long)(blockIdx.x*16 + g*4 + r)*160 + h*32 + half*16 + ln] = f2bf(o[r]);
        }
    }
}

// ============================ FUSED: FQ-gemm + final attention + max-pool ============
// (round-2 proven version: 4 nodes / 512 threads / 8 waves, measured 187 us)
__global__ __launch_bounds__(512)
void fused_fq_attn_pool(const ushort* __restrict__ O_i, const ushort* __restrict__ O_o,
                        const ushort* __restrict__ Hi, const ushort* __restrict__ Ho,
                        const float* __restrict__ c_i, const float* __restrict__ c_o,
                        const float* __restrict__ fb, float* __restrict__ pooled,
                        int node_base)
{
    __shared__ ushort sFQ[4*32*328];
    __shared__ ushort sVt[4*160*40];
    __shared__ ushort sP [4*32*40];

    const int tid  = threadIdx.x;
    const int lane = tid & 63, wave = tid >> 6;
    const int ln = lane & 15, g = lane >> 4;
    const int wl = wave >> 2, wn = wave & 3;
    const int nl0 = blockIdx.x * 4;

    const ushort* Ow = wl ? O_o : O_i;
    const ushort* Hw = wl ? Ho  : Hi;
    const float*  cw = wl ? c_o : c_i;

    bf16x8 ofr[4][5];
#pragma unroll
    for (int nd=0; nd<4; nd++)
#pragma unroll
        for (int kc=0; kc<5; kc++)
            ofr[nd][kc] = *(const bf16x8*)(Ow + ((long)(nl0+nd)*16 + ln)*160 + kc*32 + g*8);

    bf16x8 hf[5], hn[5];
#pragma unroll
    for (int kc=0; kc<5; kc++)
        hf[kc] = *(const bf16x8*)(Hw + (long)(wn*16 + ln)*160 + kc*32 + g*8);

    for (int t=0; t<8; t++){
        const int cg  = t*4 + wn;
        const int cgn = cg + 4;
        if (t < 7 && cgn < 30){
            const ushort* hrow = Hw + (long)(cgn*16 + ln)*160;
#pragma unroll
            for (int kc=0; kc<5; kc++)
                hn[kc] = *(const bf16x8*)(hrow + kc*32 + g*8);
        }

        if (cg < 30){
            f32x4 acc[4];
#pragma unroll
            for (int nd=0; nd<4; nd++)
#pragma unroll
                for (int r=0;r<4;r++) acc[nd][r] = 0.f;

#pragma unroll
            for (int kc=0; kc<5; kc++)
#pragma unroll
                for (int nd=0; nd<4; nd++)
                    acc[nd] = __builtin_amdgcn_mfma_f32_16x16x32_bf16(hf[kc], ofr[nd][kc], acc[nd], 0,0,0);

            const int cb0 = cg*16 + g*4;
            float4 cb = *(const float4*)(cw + cb0);
            if (cg < 20){
#pragma unroll
                for (int nd=0; nd<4; nd++){
                    ushort4 w4;
                    w4.x = f2bf(acc[nd][0] + cb.x);
                    w4.y = f2bf(acc[nd][1] + cb.y);
                    w4.z = f2bf(acc[nd][2] + cb.z);
                    w4.w = f2bf(acc[nd][3] + cb.w);
                    *(ushort4*)(sFQ + nd*10496 + (wl*16 + ln)*328 + cb0) = w4;
                }
            } else {
                const int c0 = cb0 - 320;
#pragma unroll
                for (int nd=0; nd<4; nd++){
                    sVt[nd*6400 + (c0+0)*40 + wl*16 + ln] = f2bf(acc[nd][0] + cb.x);
                    sVt[nd*6400 + (c0+1)*40 + wl*16 + ln] = f2bf(acc[nd][1] + cb.y);
                    sVt[nd*6400 + (c0+2)*40 + wl*16 + ln] = f2bf(acc[nd][2] + cb.z);
                    sVt[nd*6400 + (c0+3)*40 + wl*16 + ln] = f2bf(acc[nd][3] + cb.w);
                }
            }
        }
#pragma unroll
        for (int kc=0; kc<5; kc++) hf[kc] = hn[kc];
    }
    __syncthreads();

    const int nd = wave >> 1, th = wave & 1;
    const ushort* myQ = sFQ + nd*10496;
    const ushort* myV = sVt + nd*6400;
    ushort*       myP = sP  + nd*1280;

    f32x4 sc[2];
#pragma unroll
    for (int tj=0; tj<2; tj++){
        f32x4 a = {0.f,0.f,0.f,0.f};
#pragma unroll
        for (int kc=0; kc<5; kc++){
            bf16x8 ka = *(const bf16x8*)(myQ + (tj*16+ln)*328 + 160 + kc*32 + g*8);
            bf16x8 qb = *(const bf16x8*)(myQ + (th*16+ln)*328 +       kc*32 + g*8);
            a = __builtin_amdgcn_mfma_f32_16x16x32_bf16(ka, qb, a, 0,0,0);
        }
        sc[tj] = a;
    }

    const float scale = 0.07905694150420949f;
    {
        float x[2][4], m = -1e30f;
#pragma unroll
        for (int tj=0; tj<2; tj++)
#pragma unroll
            for (int r=0;r<4;r++){ x[tj][r] = sc[tj][r]*scale; m = fmaxf(m, x[tj][r]); }
        m = fmaxf(m, __shfl_xor(m, 16));
        m = fmaxf(m, __shfl_xor(m, 32));
        float sum = 0.f;
#pragma unroll
        for (int tj=0; tj<2; tj++)
#pragma unroll
            for (int r=0;r<4;r++){ x[tj][r] = __expf(x[tj][r]-m); sum += x[tj][r]; }
        sum += __shfl_xor(sum, 16);
        sum += __shfl_xor(sum, 32);
        float inv = 1.f/sum;
#pragma unroll
        for (int tj=0; tj<2; tj++){
            ushort4 pw;
            pw.x = f2bf(x[tj][0]*inv); pw.y = f2bf(x[tj][1]*inv);
            pw.z = f2bf(x[tj][2]*inv); pw.w = f2bf(x[tj][3]*inv);
            *(ushort4*)(myP + (th*16+ln)*40 + tj*16 + g*4) = pw;
        }
    }
    __syncthreads();

    bf16x8 ap[2];
#pragma unroll
    for (int mi=0; mi<2; mi++)
        ap[mi] = *(const bf16x8*)(myP + (mi*16+ln)*40 + g*8);

    const long node = (long)node_base + nl0 + nd;
#pragma unroll
    for (int nt5=0; nt5<5; nt5++){
        const int nt = th*5 + nt5;
        bf16x8 bv = *(const bf16x8*)(myV + (nt*16+ln)*40 + g*8);
        float vmax = -1e30f;
#pragma unroll
        for (int mi=0; mi<2; mi++){
            f32x4 o = {0.f,0.f,0.f,0.f};
            o = __builtin_amdgcn_mfma_f32_16x16x32_bf16(ap[mi], bv, o, 0,0,0);
#pragma unroll
            for (int r=0;r<4;r++) vmax = fmaxf(vmax, o[r]);
        }
        vmax = fmaxf(vmax, __shfl_xor(vmax, 16));
        vmax = fmaxf(vmax, __shfl_xor(vmax, 32));
        if (g == 0){
            int col = nt*16 + ln;
            pooled[node*160 + col] = vmax + fb[col];
        }
    }
}

// ============================ host ============================
extern "C" void kernel_launch(void* const* d_in, const int* in_sizes, int n_in,
                              void* d_out, int out_size, void* d_ws, size_t ws_size,
                              hipStream_t stream)
{
    const float* X       = (const float*)d_in[0];
    const int*   in_idx  = (const int*)  d_in[1];
    const int*   out_idx = (const int*)  d_in[2];
    const float* iWq     = (const float*)d_in[3];
    const float* iWk     = (const float*)d_in[4];
    const float* iWv     = (const float*)d_in[5];
    const float* i_in_w  = (const float*)d_in[6];
    const float* i_in_b  = (const float*)d_in[7];
    const float* i_out_w = (const float*)d_in[8];
    const float* i_out_b = (const float*)d_in[9];
    const float* oWq     = (const float*)d_in[10];
    const float* oWk     = (const float*)d_in[11];
    const float* oWv     = (const float*)d_in[12];
    const float* o_in_w  = (const float*)d_in[13];
    const float* o_in_b  = (const float*)d_in[14];
    const float* o_out_w = (const float*)d_in[15];
    const float* o_out_b = (const float*)d_in[16];
    const float* f_in_w  = (const float*)d_in[17];
    const float* f_in_b  = (const float*)d_in[18];
    const float* f_out_w = (const float*)d_in[19];
    const float* f_out_b = (const float*)d_in[20];
    const float* lin_w   = (const float*)d_in[21];
    const float* lin_b   = (const float*)d_in[22];

    float* ws = (float*)d_ws;
    float* pooled = ws;                           // 32768*160 fp32
    float* c_i    = pooled + 5242880;             // 480 (folded)
    float* c_o    = c_i + 480;
    float* cvt_i  = c_o + 480;                    // 480 raw
    float* cvt_o  = cvt_i + 480;
    float* Hvt_i  = cvt_o + 480;                  // 160x160 fp32
    float* Hvt_o  = Hvt_i + 25600;
    ushort* ub    = (ushort*)(Hvt_o + 25600);
    ushort* Xb    = ub;                           // 32768*160 bf16
    ushort* XPb_i = Xb + 5242880;                 // 32768*480 bf16
    ushort* XPb_o = XPb_i + 15728640;
    ushort* Wci_h = XPb_o + 15728640;             // 76800 each
    ushort* Wco_h = Wci_h + 76800;
    ushort* Hi_h  = Wco_h + 76800;
    ushort* Ho_h  = Hi_h  + 76800;
    ushort* li_h  = Ho_h  + 76800;                // 25600 each
    ushort* li_l  = li_h  + 25600;
    ushort* sb_us = li_l + 25600;
    const unsigned long long fixed = 23825280ULL; // floats

    size_t avail = ws_size / 4;
    int ns = 32768;
    while (ns > 64 && fixed + 2560ULL*ns > avail) ns >>= 1;

    ushort* O_i = sb_us;                          // ns*16*160
    ushort* O_o = O_i + (size_t)2560*ns;

    prep_combined_bf<<<300,NTH,0,stream>>>(iWq,iWk,iWv,i_in_w, Wci_h);
    prep_combined_bf<<<300,NTH,0,stream>>>(oWq,oWk,oWv,o_in_w, Wco_h);
    prep_H_split<<<300,NTH,0,stream>>>(f_in_w, i_out_w, Hi_h, Hvt_i);
    prep_H_split<<<300,NTH,0,stream>>>(f_in_w, o_out_w, Ho_h, Hvt_o);
    prep_H_fold<<<100,NTH,0,stream>>>(f_out_w, Hvt_i, Hi_h);
    prep_H_fold<<<100,NTH,0,stream>>>(f_out_w, Hvt_o, Ho_h);
    prep_cvec<<<2,NTH,0,stream>>>(f_in_w, i_out_b, f_in_b, cvt_i);
    prep_cvec<<<2,NTH,0,stream>>>(f_in_w, o_out_b, f_in_b, cvt_o);
    prep_cvec_fold<<<2,NTH,0,stream>>>(f_out_w, cvt_i, c_i);
    prep_cvec_fold<<<2,NTH,0,stream>>>(f_out_w, cvt_o, c_o);
    prep_conv_bf2<<<100,NTH,0,stream>>>(lin_w, li_h, li_l, 25600);
    prep_conv_bf1<<<20480,NTH,0,stream>>>(X, Xb, 5242880);

    // XP = Xb @ Wc^T + in_b  -> bf16 (both layers via z)
    dim3 g1(256, 3, 2);
    gemm_bf<<<g1,NTH,0,stream>>>(Xb, Xb, Wci_h, Wco_h, i_in_b, o_in_b,
                                 XPb_i, XPb_o, 480);

    int S = 32768 / ns;
    for (int s=0;s<S;s++){
        int base = s*ns;
        dim3 ga(ns, 2);
        attn_layer_mfma<<<ga,NTH,0,stream>>>(XPb_i, XPb_o, in_idx, out_idx, O_i, O_o, base);
        fused_fq_attn_pool<<<ns/4,512,0,stream>>>(O_i, O_o, Hi_h, Ho_h, c_i, c_o,
                                                  f_out_b, pooled, base);
    }

    // out = ELU(pooled @ lin_w^T + lin_b)  fp32, split-x3
    dim3 g6(256, 1);
    gemm_mfma_lin<<<g6,NTH,0,stream>>>(pooled, li_h, li_l, lin_b, (float*)d_out, 160);
}